// Round 11
// baseline (304.007 us; speedup 1.0000x reference)
//
#include <hip/hip_runtime.h>
#include <math.h>

#define NPTS 524288
#define LOG2T 19
#define TSIZE (1u << LOG2T)
#define TMASK (TSIZE - 1u)

typedef unsigned int uint32;
typedef unsigned short ushort16;

typedef __attribute__((ext_vector_type(8))) short short8;
typedef __attribute__((ext_vector_type(4))) float f32x4;

__device__ __forceinline__ float bf2f(ushort16 u) {
    union { uint32 i; float f; } v; v.i = ((uint32)u) << 16; return v.f;
}
__device__ __forceinline__ ushort16 f2bf(float f) {
    union { float f; uint32 i; } v; v.f = f;
    uint32 r = v.i + 0x7fffu + ((v.i >> 16) & 1u);   // RNE
    return (ushort16)(r >> 16);
}
// Packed fp32x2 -> bf16x2 via single HW instruction (RNE, same as f2bf).
__device__ __forceinline__ uint32 pack2(float a, float b) {
    uint32 r;
    asm("v_cvt_pk_bf16_f32 %0, %1, %2" : "=v"(r) : "v"(a), "v"(b));
    return r;
}
// dtype-flexible scalar load: fp32 or bf16 per runtime flag (block-uniform)
__device__ __forceinline__ float ldin(const void* p, int i, bool f32) {
    return f32 ? ((const float*)p)[i] : bf2f(((const ushort16*)p)[i]);
}

struct Scal16 { float s[16]; };
struct Freq4  { float f[4]; };
struct HashP  { float s[16]; int dD[8]; int doff[8]; };   // dD/doff valid for lvl<5
struct DenseP { int dD[6]; int pfx[7]; };                 // levels 0..4 used; pfx[5]=end

// ---------------------------------------------------------------------------
// Dense-level interpolation from the xy-patch array (2x 16B loads). Returns
// packed bf16 pair.
// ---------------------------------------------------------------------------
__device__ __forceinline__ uint32 dense_interp(const uint4* __restrict__ dense4,
                                               float x, float y, float z,
                                               float s, int D, int doff) {
    float sx = x * s, sy = y * s, sz = z * s;
    float fx = floorf(sx), fy = floorf(sy), fz = floorf(sz);
    float cx = ceilf(sx), cy = ceilf(sy), cz = ceilf(sz);
    float ox = sx - fx, oy = sy - fy, oz = sz - fz;
    float wx0 = 1.f - ox, wy0 = 1.f - oy, wz0 = 1.f - oz;

    int D2 = D * D;
    int fxi = (int)fx, fyi = (int)fy, fzi = (int)fz;
    bool dxb = ((int)cx != fxi);
    bool dyb = ((int)cy != fyi);
    bool dzb = ((int)cz != fzi);
    const uint4* dp4 = dense4 + doff;
    int i0 = fxi + fyi * D + fzi * D2;
    uint4 P0 = dp4[i0];
    uint4 P1 = dp4[i0 + (dzb ? D2 : 0)];

    float a0 = 0.f, a1 = 0.f;
    {   // by=0, bz=0
        uint32 fv = P0.x, cv = dxb ? P0.y : P0.x;
        float w = wy0 * wz0;
        a0 += w * (wx0 * bf2f((ushort16)(fv & 0xffffu)) + ox * bf2f((ushort16)(cv & 0xffffu)));
        a1 += w * (wx0 * bf2f((ushort16)(fv >> 16))     + ox * bf2f((ushort16)(cv >> 16)));
    }
    {   // by=1, bz=0
        uint32 fv = dyb ? P0.z : P0.x;
        uint32 cv = dyb ? (dxb ? P0.w : P0.z) : (dxb ? P0.y : P0.x);
        float w = oy * wz0;
        a0 += w * (wx0 * bf2f((ushort16)(fv & 0xffffu)) + ox * bf2f((ushort16)(cv & 0xffffu)));
        a1 += w * (wx0 * bf2f((ushort16)(fv >> 16))     + ox * bf2f((ushort16)(cv >> 16)));
    }
    {   // by=0, bz=1
        uint32 fv = P1.x, cv = dxb ? P1.y : P1.x;
        float w = wy0 * oz;
        a0 += w * (wx0 * bf2f((ushort16)(fv & 0xffffu)) + ox * bf2f((ushort16)(cv & 0xffffu)));
        a1 += w * (wx0 * bf2f((ushort16)(fv >> 16))     + ox * bf2f((ushort16)(cv >> 16)));
    }
    {   // by=1, bz=1
        uint32 fv = dyb ? P1.z : P1.x;
        uint32 cv = dyb ? (dxb ? P1.w : P1.z) : (dxb ? P1.y : P1.x);
        float w = oy * oz;
        a0 += w * (wx0 * bf2f((ushort16)(fv & 0xffffu)) + ox * bf2f((ushort16)(cv & 0xffffu)));
        a1 += w * (wx0 * bf2f((ushort16)(fv >> 16))     + ox * bf2f((ushort16)(cv >> 16)));
    }
    return pack2(a0, a1);
}

// ---------------------------------------------------------------------------
// Kernel P: merged one-time prep.
// bid < 5632 : fp32 table -> packed-bf16 table, levels 5..15 (no-op for bf16)
// bid >= 5632: densify levels 0..4 into grid-ordered xy-patch entries
//              (3.3 MB total -> L2-co-resident in k_mlp; lvl 5 moved to hash
//              path after round-10 showed its 4.19 MB slice thrashes L2)
// ---------------------------------------------------------------------------
__global__ __launch_bounds__(256) void k_prep(const void* __restrict__ pos,
                                              const void* __restrict__ tbl,
                                              uint4* __restrict__ tbl2F,
                                              uint4* __restrict__ dense4,
                                              DenseP dp) {
    __shared__ int sFlag;
    int tid = threadIdx.x;
    if (tid < 64) {
        const ushort16* ph = (const ushort16*)pos;
        float v0 = bf2f(ph[tid]), v1 = bf2f(ph[tid + 64]);
        bool odd = !(fabsf(v0) <= 4.f) || !(fabsf(v1) <= 4.f);
        unsigned long long m = __ballot(odd);
        if (tid == 0) sFlag = (m != 0ull) ? 1 : 0;
    }
    __syncthreads();
    const bool f32 = (sFlag != 0);

    if (blockIdx.x < 5632) {
        // ---- cvt role: pack levels 5..15 (11*TSIZE entries, 4 per thread) ----
        if (!f32) return;
        const float4* tf4 = (const float4*)tbl;
        size_t g = (size_t)blockIdx.x * 256 + tid;        // [0, 11*TSIZE/4)
        size_t srcBase = (size_t)5 * TSIZE / 2;           // float4 units
        float4 v0 = tf4[srcBase + 2 * g];
        float4 v1 = tf4[srcBase + 2 * g + 1];
        uint4 o;
        o.x = pack2(v0.x, v0.y); o.y = pack2(v0.z, v0.w);
        o.z = pack2(v1.x, v1.y); o.w = pack2(v1.z, v1.w);
        tbl2F[g] = o;
        return;
    }

    int e = (blockIdx.x - 5632) * 256 + tid;
    if (e >= dp.pfx[5]) return;
    int l = 0;
#pragma unroll
    for (int k = 1; k < 5; ++k) l += (e >= dp.pfx[k]) ? 1 : 0;
    int c = e - dp.pfx[l];
    int D = dp.dD[l], D2 = D * D;
    int cz = c / D2; int rm = c - cz * D2;
    int cy = rm / D; int cx = rm - cy * D;

    uint32 base = (uint32)l << LOG2T;
    uint32 hz  = (uint32)cz * 805459861u;
    uint32 hy0 = (uint32)cy * 2654435761u;
    uint32 hy1 = (uint32)(cy + 1) * 2654435761u;
    uint32 h00 = ((((uint32)cx)       ^ hy0 ^ hz) & TMASK) + base;
    uint32 h10 = ((((uint32)(cx + 1)) ^ hy0 ^ hz) & TMASK) + base;
    uint32 h01 = ((((uint32)cx)       ^ hy1 ^ hz) & TMASK) + base;
    uint32 h11 = ((((uint32)(cx + 1)) ^ hy1 ^ hz) & TMASK) + base;

    uint4 o;
    if (f32) {
        const float2* t2 = (const float2*)tbl;
        float2 a = t2[h00], b = t2[h10], cc = t2[h01], d = t2[h11];
        o.x = pack2(a.x, a.y); o.y = pack2(b.x, b.y);
        o.z = pack2(cc.x, cc.y); o.w = pack2(d.x, d.y);
    } else {
        const uint32* t1 = (const uint32*)tbl;
        o.x = t1[h00]; o.y = t1[h10]; o.z = t1[h01]; o.w = t1[h11];
    }
    dense4[e] = o;
}

// ---------------------------------------------------------------------------
// Kernel F: balanced hashed encode, levels 5..15 in ONE dispatch.
// XCD k (= bid&7) gets 2816 contiguous (lvl,chunk) slots = 1.375 levels;
// the CONCURRENT working window spans <=2 table slices = 4 MB = L2-resident
// (round-4-proven regime). Per-XCD time scales 11/10 of the measured
// 98.5-us floor -> ~108 us.
// ---------------------------------------------------------------------------
__global__ __launch_bounds__(256) void k_hashB(const void* __restrict__ pos,
                                               const void* __restrict__ tbl,
                                               const uint32* __restrict__ tbl2F,
                                               uint32* __restrict__ enc,
                                               HashP hp) {
    __shared__ __align__(16) uint4 sPosQ[192];
    __shared__ int sFlag;
    int tid = threadIdx.x;
    if (tid < 64) {
        const ushort16* ph = (const ushort16*)pos;
        float v0 = bf2f(ph[tid]), v1 = bf2f(ph[tid + 64]);
        bool odd = !(fabsf(v0) <= 4.f) || !(fabsf(v1) <= 4.f);
        unsigned long long m = __ballot(odd);
        if (tid == 0) sFlag = (m != 0ull) ? 1 : 0;
    }
    __syncthreads();
    const bool f32 = (sFlag != 0);

    int xcd = blockIdx.x & 7;
    int slot = blockIdx.x >> 3;               // [0, 2816)
    int W = xcd * 2816 + slot;                // [0, 22528)
    int lvl = 5 + (W >> 11);                  // 5..15
    int chunk = W & 2047;
    int p0 = chunk * 256;
    int pt = p0 + tid;

    {
        int n16 = f32 ? 192 : 96;
        const uint4* src = (const uint4*)((const char*)pos + (size_t)p0 * (f32 ? 12 : 6));
        for (int i = tid; i < n16; i += 256) sPosQ[i] = src[i];
    }
    __syncthreads();

    float x, y, z;
    if (f32) {
        const float* pf = (const float*)sPosQ;
        x = pf[3 * tid]; y = pf[3 * tid + 1]; z = pf[3 * tid + 2];
    } else {
        const ushort16* ph2 = (const ushort16*)sPosQ;
        x = bf2f(ph2[3 * tid]); y = bf2f(ph2[3 * tid + 1]); z = bf2f(ph2[3 * tid + 2]);
    }

    float s = hp.s[lvl];
    float sx = x * s, sy = y * s, sz = z * s;
    float fx = floorf(sx), fy = floorf(sy), fz = floorf(sz);
    float cx = ceilf(sx), cy = ceilf(sy), cz = ceilf(sz);   // ceil, NOT floor+1 (matches ref)
    float ox = sx - fx, oy = sy - fy, oz = sz - fz;
    float wx0 = 1.f - ox, wy0 = 1.f - oy, wz0 = 1.f - oz;

    const uint32* tp; uint32 base;
    if (f32) { tp = tbl2F; base = (uint32)(lvl - 5) << LOG2T; }
    else     { tp = (const uint32*)tbl; base = (uint32)lvl << LOG2T; }
    uint32 hx0 = (uint32)(int)fx;                       // prime[0] = 1
    uint32 hx1 = (uint32)(int)cx;
    uint32 hy0 = (uint32)(int)fy * 2654435761u;
    uint32 hy1 = (uint32)(int)cy * 2654435761u;
    uint32 hz0 = (uint32)(int)fz * 805459861u;
    uint32 hz1 = (uint32)(int)cz * 805459861u;

    float a0 = 0.f, a1 = 0.f;
#pragma unroll
    for (int yz = 0; yz < 4; ++yz) {
        uint32 m = ((yz & 1) ? hy1 : hy0) ^ ((yz & 2) ? hz1 : hz0);
        float wyz = ((yz & 1) ? oy : wy0) * ((yz & 2) ? oz : wz0);
        uint32 i0 = ((hx0 ^ m) & TMASK) + base;
        uint32 i1 = ((hx1 ^ m) & TMASK) + base;
        uint32 d0, d1;
        if (i1 == (i0 ^ 1u)) {              // even-fx pair: one 8 B load
            uint2 pv = *(const uint2*)(tp + (i0 & ~1u));
            d0 = (i0 & 1u) ? pv.y : pv.x;
            d1 = (i0 & 1u) ? pv.x : pv.y;
        } else {                            // unpaired: two 4 B loads
            d0 = tp[i0]; d1 = tp[i1];
        }
        a0 += wyz * (wx0 * bf2f((ushort16)(d0 & 0xffffu)) + ox * bf2f((ushort16)(d1 & 0xffffu)));
        a1 += wyz * (wx0 * bf2f((ushort16)(d0 >> 16))     + ox * bf2f((ushort16)(d1 >> 16)));
    }
    enc[(size_t)lvl * NPTS + pt] = pack2(a0, a1);
}

// ---------------------------------------------------------------------------
// LEGACY Kernel A (fallback when ws too small): level-major hash encode,
// writes ALL 16 levels (fallback k_mlp stages them all; denseMode=0).
// ---------------------------------------------------------------------------
__global__ __launch_bounds__(256) void k_hash(const void* __restrict__ pos,
                                              const void* __restrict__ tbl,
                                              uint32* __restrict__ enc,
                                              Scal16 sc) {
    __shared__ int sFlag;
    int tid = threadIdx.x;
    if (tid < 64) {
        const ushort16* ph = (const ushort16*)pos;
        float v0 = bf2f(ph[tid]), v1 = bf2f(ph[tid + 64]);
        bool odd = !(fabsf(v0) <= 4.f) || !(fabsf(v1) <= 4.f);
        unsigned long long m = __ballot(odd);
        if (tid == 0) sFlag = (m != 0ull) ? 1 : 0;
    }
    __syncthreads();
    const bool f32 = (sFlag != 0);

    int lvl = ((blockIdx.x >> 14) << 3) + (blockIdx.x & 7);
    int pt = ((blockIdx.x >> 3) & 2047) * 256 + tid;

    float s = sc.s[lvl];
    float x = ldin(pos, 3 * pt, f32), y = ldin(pos, 3 * pt + 1, f32), z = ldin(pos, 3 * pt + 2, f32);
    float sx = x * s, sy = y * s, sz = z * s;
    float fx = floorf(sx), fy = floorf(sy), fz = floorf(sz);
    float cx = ceilf(sx), cy = ceilf(sy), cz = ceilf(sz);
    float ox = sx - fx, oy = sy - fy, oz = sz - fz;
    uint32 hx0 = (uint32)(int)fx;
    uint32 hx1 = (uint32)(int)cx;
    uint32 hy0 = (uint32)(int)fy * 2654435761u;
    uint32 hy1 = (uint32)(int)cy * 2654435761u;
    uint32 hz0 = (uint32)(int)fz * 805459861u;
    uint32 hz1 = (uint32)(int)cz * 805459861u;
    uint32 base = (uint32)lvl << LOG2T;
    float wx0 = 1.f - ox, wy0 = 1.f - oy, wz0 = 1.f - oz;

    float a0 = 0.f, a1 = 0.f;
    if (f32) {
        const float* tf = (const float*)tbl;
#pragma unroll
        for (int yz = 0; yz < 4; ++yz) {
            uint32 m = ((yz & 1) ? hy1 : hy0) ^ ((yz & 2) ? hz1 : hz0);
            float wyz = ((yz & 1) ? oy : wy0) * ((yz & 2) ? oz : wz0);
            uint32 i0 = ((hx0 ^ m) & TMASK) + base;
            uint32 i1 = ((hx1 ^ m) & TMASK) + base;
            float4 pv = *(const float4*)(tf + (size_t)(i0 & ~1u) * 2);
            bool lo = !(i0 & 1u);
            float f0 = lo ? pv.x : pv.z, f1 = lo ? pv.y : pv.w;
            float c0, c1;
            if (i1 == (i0 ^ 1u)) { c0 = lo ? pv.z : pv.x; c1 = lo ? pv.w : pv.y; }
            else { float2 tv = ((const float2*)tbl)[i1]; c0 = tv.x; c1 = tv.y; }
            a0 += wyz * (wx0 * f0 + ox * c0);
            a1 += wyz * (wx0 * f1 + ox * c1);
        }
    } else {
#pragma unroll
        for (int cr = 0; cr < 8; ++cr) {
            uint32 h = ((cr & 1) ? hx1 : hx0) ^ ((cr & 2) ? hy1 : hy0) ^ ((cr & 4) ? hz1 : hz0);
            uint32 idx = (h & TMASK) + base;
            uint32 dv = ((const uint32*)tbl)[idx];
            float w = ((cr & 1) ? ox : wx0) * ((cr & 2) ? oy : wy0) * ((cr & 4) ? oz : wz0);
            a0 += w * bf2f((ushort16)(dv & 0xffffu));
            a1 += w * bf2f((ushort16)(dv >> 16));
        }
    }
    enc[(size_t)lvl * NPTS + pt] = pack2(a0, a1);
}

// ---------------------------------------------------------------------------
// Kernel B: R8 structure. Round-11 change: dense leg now covers levels 0..4
// only (3.3 MB dense4 -> L2-co-resident, gathers become L2 hits); level 5
// moved to k_hashB. Hashed staging covers 11 levels (352 uint4 jobs).
// denseMode=0 restores the legacy full-stage path (fallback).
// ---------------------------------------------------------------------------
#define STRY 76
#define STRW0 40
#define STRW12 76
#define STRWR 104
#define MSTRX 100
#define PPI 128                 // points per iteration
#define NIT (NPTS / PPI)

__global__ __launch_bounds__(512) void k_mlp(
    const void* __restrict__ pos,   // dtype detection + pos staging
    const uint32* __restrict__ enc, const void* __restrict__ dirs,
    const uint4* __restrict__ dense4,
    const void* __restrict__ w0, const void* __restrict__ b0,
    const void* __restrict__ w1, const void* __restrict__ b1,
    const void* __restrict__ w2, const void* __restrict__ b2,
    const void* __restrict__ wr, const void* __restrict__ br,
    const void* __restrict__ wc, const void* __restrict__ bc,
    const void* __restrict__ wd, const void* __restrict__ bd,
    void* __restrict__ out, Freq4 fq, HashP hp, int denseMode)
{
    __shared__ __align__(16) ushort16 sX[PPI * MSTRX];
    __shared__ __align__(16) ushort16 sY[PPI * STRY];
    __shared__ __align__(16) ushort16 sW0[64 * STRW0];
    __shared__ __align__(16) ushort16 sW1[64 * STRW12];
    __shared__ __align__(16) ushort16 sW2[64 * STRW12];
    __shared__ __align__(16) ushort16 sWR[32 * STRWR];
    __shared__ __align__(16) ushort16 sW4[16 * STRWR];
    __shared__ __align__(16) float sB0[64], sB1[64], sB2[64], sBR[32], sFB[4];
    __shared__ int sFlag;

    int tid = threadIdx.x;

    if (tid < 64) {
        const ushort16* ph = (const ushort16*)pos;
        float v0 = bf2f(ph[tid]), v1 = bf2f(ph[tid + 64]);
        bool odd = !(fabsf(v0) <= 4.f) || !(fabsf(v1) <= 4.f);
        unsigned long long m = __ballot(odd);
        if (tid == 0) sFlag = (m != 0ull) ? 1 : 0;
    }
    __syncthreads();
    const bool f32 = (sFlag != 0);

    // ---- stage weights once (transpose to [n][k], bf16) ----
    for (int i = tid; i < 2048; i += 512) { int k = i >> 6, n = i & 63; sW0[n * STRW0 + k] = f2bf(ldin(w0, i, f32)); }
    for (int i = tid; i < 4096; i += 512) { int k = i >> 6, n = i & 63; sW1[n * STRW12 + k] = f2bf(ldin(w1, i, f32)); }
    for (int i = tid; i < 4096; i += 512) { int k = i >> 6, n = i & 63; sW2[n * STRW12 + k] = f2bf(ldin(w2, i, f32)); }
    // wr[91][32]: rows 0..26 (dir) -> k=r; rows 27..90 (base) -> k=r+5
    for (int i = tid; i < 2912; i += 512) {
        int r = i >> 5, n = i & 31; int k = (r < 27) ? r : r + 5;
        sWR[n * STRWR + k] = f2bf(ldin(wr, i, f32));
    }
    if (tid < 160) { int n = tid / 5, k = 27 + tid % 5; sWR[n * STRWR + k] = 0; }  // zero pad k=27..31
    // W4[16][96]: k 0..63 = base, k 64..95 = rgb_h; rows 0..2 = wc, row 3 = wd
    for (int i = tid; i < 1536; i += 512) {
        int n = i / 96, j = i % 96;
        float v = 0.f;
        if (n == 3 && j < 64) v = ldin(wd, j, f32);
        else if (n < 3 && j >= 64) v = ldin(wc, (j - 64) * 3 + n, f32);
        sW4[n * STRWR + j] = f2bf(v);
    }
    if (tid < 64) { sB0[tid] = ldin(b0, tid, f32); sB1[tid] = ldin(b1, tid, f32); sB2[tid] = ldin(b2, tid, f32); }
    if (tid < 32) sBR[tid] = ldin(br, tid, f32);
    if (tid < 3) sFB[tid] = ldin(bc, tid, f32);
    if (tid == 3) sFB[3] = ldin(bd, 0, f32);

    int lane = tid & 63, wv = tid >> 6;          // wv in [0,8)
    int colg = lane & 15, quad = lane >> 4;
    int myrow = wv * 16 + colg;                  // this lane's point row in [0,128)

    for (int c = blockIdx.x; c < NIT; c += gridDim.x) {
        int p0 = c * PPI;
        __syncthreads();   // B1: prev iteration finale reads done (covers weight staging on iter 0)

        if (denseMode) {
            // ---- phase A: pos -> sY scratch (ONE read of 128 pts), dir
            //      encode, hashed uint4 stage (11 levels), zero pad ----
            {
                uint4* sPosS = (uint4*)sY;               // sY not live until L0
                int n16 = f32 ? 96 : 48;
                const uint4* src = (const uint4*)((const char*)pos + (size_t)p0 * (f32 ? 12 : 6));
                for (int i = tid; i < n16; i += 512) sPosS[i] = src[i];
            }
            // hashed levels 5..15 -> sX cols 10..31 (352 uint4 jobs)
            if (tid < 352) {
                int l = tid % 11, q = tid / 11;    // q in [0,32)
                int pp = q * 4;
                uint4 e = *(const uint4*)&enc[(size_t)(5 + l) * NPTS + p0 + pp];
                *(uint32*)&sX[(pp + 0) * MSTRX + 10 + 2 * l] = e.x;
                *(uint32*)&sX[(pp + 1) * MSTRX + 10 + 2 * l] = e.y;
                *(uint32*)&sX[(pp + 2) * MSTRX + 10 + 2 * l] = e.z;
                *(uint32*)&sX[(pp + 3) * MSTRX + 10 + 2 * l] = e.w;
            }
            // dir encode (384 jobs) + zero pad (128 threads)
            if (tid < 384) {
                int p = tid / 3, i2 = tid - 3 * (tid / 3);
                float dvv = ldin(dirs, 3 * (p0 + p) + i2, f32);
                ushort16* row = &sX[p * MSTRX + 64];
                float td = 6.28318530717958647692f * dvv;
                float a0 = td * fq.f[0], a1 = td * fq.f[1], a2 = td * fq.f[2], a3 = td * fq.f[3];
                uint2 sv, cv;
                sv.x = pack2(__sinf(a0), __sinf(a1));
                sv.y = pack2(__sinf(a2), __sinf(a3));
                cv.x = pack2(__cosf(a0), __cosf(a1));
                cv.y = pack2(__cosf(a2), __cosf(a3));
                *(uint2*)&row[i2 * 4] = sv;
                *(uint2*)&row[12 + i2 * 4] = cv;
                row[24 + i2] = f2bf(dvv);
            } else {
                int p = tid - 384;   // 128 threads zero cols 91..95
                ushort16* row = &sX[p * MSTRX + 64];
#pragma unroll
                for (int j = 27; j < 32; ++j) row[j] = 0;
            }
            __syncthreads();   // B1.5: pos scratch ready

            // ---- phase B: dense levels 0..4, 640 jobs over ALL threads,
            //      pos from LDS (1-2 jobs/thread); dense4 is L2-resident ----
            for (int j = tid; j < 640; j += 512) {
                int p = j / 5, l = j - 5 * p;
                float x, y, z;
                if (f32) {
                    const float* pf = (const float*)sY;
                    x = pf[3 * p]; y = pf[3 * p + 1]; z = pf[3 * p + 2];
                } else {
                    const ushort16* ph2 = (const ushort16*)sY;
                    x = bf2f(ph2[3 * p]); y = bf2f(ph2[3 * p + 1]); z = bf2f(ph2[3 * p + 2]);
                }
                *(uint32*)&sX[p * MSTRX + 2 * l] =
                    dense_interp(dense4, x, y, z, hp.s[l], hp.dD[l], hp.doff[l]);
            }
        } else {
            // ---- legacy: stage all 16 levels from enc ----
            for (int i = tid; i < 1024; i += 512) {
                int l = i & 15, pp = (i >> 4) * 2;
                uint2 e = *(const uint2*)&enc[(size_t)l * NPTS + p0 + pp];
                *(uint32*)&sX[pp * MSTRX + 2 * l] = e.x;
                *(uint32*)&sX[(pp + 1) * MSTRX + 2 * l] = e.y;
            }
            if (tid < 384) {
                int p = tid / 3, i2 = tid - 3 * (tid / 3);
                float dvv = ldin(dirs, 3 * (p0 + p) + i2, f32);
                ushort16* row = &sX[p * MSTRX + 64];
                float td = 6.28318530717958647692f * dvv;
                float a0 = td * fq.f[0], a1 = td * fq.f[1], a2 = td * fq.f[2], a3 = td * fq.f[3];
                uint2 sv, cv;
                sv.x = pack2(__sinf(a0), __sinf(a1));
                sv.y = pack2(__sinf(a2), __sinf(a3));
                cv.x = pack2(__cosf(a0), __cosf(a1));
                cv.y = pack2(__cosf(a2), __cosf(a3));
                *(uint2*)&row[i2 * 4] = sv;
                *(uint2*)&row[12 + i2 * 4] = cv;
                row[24 + i2] = f2bf(dvv);
            } else {
                int p = tid - 384;
                ushort16* row = &sX[p * MSTRX + 64];
#pragma unroll
                for (int j = 27; j < 32; ++j) row[j] = 0;
            }
        }
        __syncthreads();   // B2: enc + dir staged (and pos scratch dead)

        // ---- L0: relu(enc @ w0 + b0) -> sY[0..63] (operand-swapped, packed WB) ----
        {
            short8 xb = *(const short8*)&sX[myrow * MSTRX + quad * 8];
#pragma unroll
            for (int nt = 0; nt < 4; ++nt) {
                short8 a = *(const short8*)&sW0[(nt * 16 + colg) * STRW0 + quad * 8];
                f32x4 acc = {0.f, 0.f, 0.f, 0.f};
                acc = __builtin_amdgcn_mfma_f32_16x16x32_bf16(a, xb, acc, 0, 0, 0);
                float4 bi = *(const float4*)&sB0[nt * 16 + quad * 4];
                uint2 o;
                o.x = pack2(fmaxf(acc[0] + bi.x, 0.f), fmaxf(acc[1] + bi.y, 0.f));
                o.y = pack2(fmaxf(acc[2] + bi.z, 0.f), fmaxf(acc[3] + bi.w, 0.f));
                *(uint2*)&sY[myrow * STRY + nt * 16 + quad * 4] = o;
            }
        }
        // ---- L1: relu(h0 @ w1 + b1) -> sX[0..63] ----
        {
            short8 xb0 = *(const short8*)&sY[myrow * STRY + quad * 8];
            short8 xb1 = *(const short8*)&sY[myrow * STRY + 32 + quad * 8];
#pragma unroll
            for (int nt = 0; nt < 4; ++nt) {
                short8 a0 = *(const short8*)&sW1[(nt * 16 + colg) * STRW12 + quad * 8];
                short8 a1 = *(const short8*)&sW1[(nt * 16 + colg) * STRW12 + 32 + quad * 8];
                f32x4 acc = {0.f, 0.f, 0.f, 0.f};
                acc = __builtin_amdgcn_mfma_f32_16x16x32_bf16(a0, xb0, acc, 0, 0, 0);
                acc = __builtin_amdgcn_mfma_f32_16x16x32_bf16(a1, xb1, acc, 0, 0, 0);
                float4 bi = *(const float4*)&sB1[nt * 16 + quad * 4];
                uint2 o;
                o.x = pack2(fmaxf(acc[0] + bi.x, 0.f), fmaxf(acc[1] + bi.y, 0.f));
                o.y = pack2(fmaxf(acc[2] + bi.z, 0.f), fmaxf(acc[3] + bi.w, 0.f));
                *(uint2*)&sX[myrow * MSTRX + nt * 16 + quad * 4] = o;
            }
        }
        // ---- L2: base = h1 @ w2 + b2 -> sY[0..63] (linear) ----
        {
            short8 xb0 = *(const short8*)&sX[myrow * MSTRX + quad * 8];
            short8 xb1 = *(const short8*)&sX[myrow * MSTRX + 32 + quad * 8];
#pragma unroll
            for (int nt = 0; nt < 4; ++nt) {
                short8 a0 = *(const short8*)&sW2[(nt * 16 + colg) * STRW12 + quad * 8];
                short8 a1 = *(const short8*)&sW2[(nt * 16 + colg) * STRW12 + 32 + quad * 8];
                f32x4 acc = {0.f, 0.f, 0.f, 0.f};
                acc = __builtin_amdgcn_mfma_f32_16x16x32_bf16(a0, xb0, acc, 0, 0, 0);
                acc = __builtin_amdgcn_mfma_f32_16x16x32_bf16(a1, xb1, acc, 0, 0, 0);
                float4 bi = *(const float4*)&sB2[nt * 16 + quad * 4];
                uint2 o;
                o.x = pack2(acc[0] + bi.x, acc[1] + bi.y);
                o.y = pack2(acc[2] + bi.z, acc[3] + bi.w);
                *(uint2*)&sY[myrow * STRY + nt * 16 + quad * 4] = o;
            }
        }
        // ---- Lr: rgb_h = [dir|base] @ wr + br -> sX[0..31] (K=96) ----
        {
            short8 xb0 = *(const short8*)&sX[myrow * MSTRX + 64 + quad * 8];
            short8 xb1 = *(const short8*)&sY[myrow * STRY + quad * 8];
            short8 xb2 = *(const short8*)&sY[myrow * STRY + 32 + quad * 8];
#pragma unroll
            for (int nt = 0; nt < 2; ++nt) {
                short8 a0 = *(const short8*)&sWR[(nt * 16 + colg) * STRWR + quad * 8];
                short8 a1 = *(const short8*)&sWR[(nt * 16 + colg) * STRWR + 32 + quad * 8];
                short8 a2 = *(const short8*)&sWR[(nt * 16 + colg) * STRWR + 64 + quad * 8];
                f32x4 acc = {0.f, 0.f, 0.f, 0.f};
                acc = __builtin_amdgcn_mfma_f32_16x16x32_bf16(a0, xb0, acc, 0, 0, 0);
                acc = __builtin_amdgcn_mfma_f32_16x16x32_bf16(a1, xb1, acc, 0, 0, 0);
                acc = __builtin_amdgcn_mfma_f32_16x16x32_bf16(a2, xb2, acc, 0, 0, 0);
                float4 bi = *(const float4*)&sBR[nt * 16 + quad * 4];
                uint2 o;
                o.x = pack2(acc[0] + bi.x, acc[1] + bi.y);
                o.y = pack2(acc[2] + bi.z, acc[3] + bi.w);
                *(uint2*)&sX[myrow * MSTRX + nt * 16 + quad * 4] = o;
            }
        }
        // ---- finale: D' = W4 @ [base|rgb_h]^T; quad0 lane holds (r,g,b,dd) ----
        {
            short8 xb0 = *(const short8*)&sY[myrow * STRY + quad * 8];        // base 0..31
            short8 xb1 = *(const short8*)&sY[myrow * STRY + 32 + quad * 8];   // base 32..63
            short8 xb2 = *(const short8*)&sX[myrow * MSTRX + quad * 8];       // rgb_h 0..31
            short8 a0 = *(const short8*)&sW4[colg * STRWR + quad * 8];
            short8 a1 = *(const short8*)&sW4[colg * STRWR + 32 + quad * 8];
            short8 a2 = *(const short8*)&sW4[colg * STRWR + 64 + quad * 8];
            f32x4 acc = {0.f, 0.f, 0.f, 0.f};
            acc = __builtin_amdgcn_mfma_f32_16x16x32_bf16(a0, xb0, acc, 0, 0, 0);
            acc = __builtin_amdgcn_mfma_f32_16x16x32_bf16(a1, xb1, acc, 0, 0, 0);
            acc = __builtin_amdgcn_mfma_f32_16x16x32_bf16(a2, xb2, acc, 0, 0, 0);
            if (quad == 0) {
                float r0 = acc[0] + sFB[0], r1 = acc[1] + sFB[1], r2 = acc[2] + sFB[2], dd = acc[3] + sFB[3];
                r0 = 1.f / (1.f + expf(-r0));
                r1 = 1.f / (1.f + expf(-r1));
                r2 = 1.f / (1.f + expf(-r2));
                float sp = (dd > 0.f) ? (dd + log1pf(expf(-dd))) : log1pf(expf(dd));
                int pt = p0 + myrow;
                if (f32) {
                    float4 o4; o4.x = r0; o4.y = r1; o4.z = r2; o4.w = sp;
                    ((float4*)out)[pt] = o4;
                } else {
                    uint2 o; o.x = pack2(r0, r1); o.y = pack2(r2, sp);
                    ((uint2*)out)[pt] = o;
                }
            }
        }
        // no B3: finale reads only own-wave rows; B1 protects next staging
    }
}

// ---------------------------------------------------------------------------
// Fallback: the round-3 PASSING fully fused kernel (used if ws too small).
// ---------------------------------------------------------------------------
#define FSTRX 104
__global__ __launch_bounds__(256) void k_fused(
    const void* __restrict__ pos, const void* __restrict__ dirs,
    const void* __restrict__ tbl,
    const void* __restrict__ w0, const void* __restrict__ b0,
    const void* __restrict__ w1, const void* __restrict__ b1,
    const void* __restrict__ w2, const void* __restrict__ b2,
    const void* __restrict__ wr, const void* __restrict__ br,
    const void* __restrict__ wc, const void* __restrict__ bc,
    const void* __restrict__ wd, const void* __restrict__ bd,
    void* __restrict__ out, Scal16 sc, Freq4 fq)
{
    __shared__ __align__(16) ushort16 sX[64 * FSTRX];
    __shared__ __align__(16) ushort16 sY[64 * STRY];
    __shared__ __align__(16) ushort16 sW0[64 * STRW0];
    __shared__ __align__(16) ushort16 sW1[64 * STRW12];
    __shared__ __align__(16) ushort16 sW2[64 * STRW12];
    __shared__ __align__(16) ushort16 sWR[32 * STRWR];
    __shared__ float sB0[64], sB1[64], sB2[64], sBR[32];
    __shared__ float sWCf[100];
    __shared__ float sWDf[64];
    __shared__ float sPosF[192];
    __shared__ int sFlag;

    int tid = threadIdx.x;
    if (tid < 64) {
        const ushort16* ph = (const ushort16*)pos;
        float v0 = bf2f(ph[tid]), v1 = bf2f(ph[tid + 64]);
        bool odd = !(fabsf(v0) <= 4.f) || !(fabsf(v1) <= 4.f);
        unsigned long long m = __ballot(odd);
        if (tid == 0) sFlag = (m != 0ull) ? 1 : 0;
    }
    __syncthreads();
    const bool f32 = (sFlag != 0);

    for (int i = tid; i < 2048; i += 256) { int k = i >> 6, n = i & 63; sW0[n * STRW0 + k] = f2bf(ldin(w0, i, f32)); }
    for (int i = tid; i < 4096; i += 256) { int k = i >> 6, n = i & 63; sW1[n * STRW12 + k] = f2bf(ldin(w1, i, f32)); }
    for (int i = tid; i < 4096; i += 256) { int k = i >> 6, n = i & 63; sW2[n * STRW12 + k] = f2bf(ldin(w2, i, f32)); }
    for (int i = tid; i < 2912; i += 256) {
        int r = i >> 5, n = i & 31; int k = (r < 27) ? r : r + 5;
        sWR[n * STRWR + k] = f2bf(ldin(wr, i, f32));
    }
    if (tid < 160) { int n = tid / 5, k = 27 + tid % 5; sWR[n * STRWR + k] = 0; }
    if (tid < 64) { sB0[tid] = ldin(b0, tid, f32); sB1[tid] = ldin(b1, tid, f32);
                    sB2[tid] = ldin(b2, tid, f32); sWDf[tid] = ldin(wd, tid, f32); }
    if (tid < 32) sBR[tid] = ldin(br, tid, f32);
    if (tid < 96) sWCf[tid] = ldin(wc, tid, f32);
    if (tid == 96) { sWCf[96] = ldin(bc, 0, f32); sWCf[97] = ldin(bc, 1, f32);
                     sWCf[98] = ldin(bc, 2, f32); sWCf[99] = ldin(bd, 0, f32); }

    int lane = tid & 63, wv = tid >> 6;
    int colg = lane & 15, quad = lane >> 4;
    int myl = tid & 15;
    float mys = sc.s[myl];
    uint32 mybase = (uint32)myl << LOG2T;

    for (int c = blockIdx.x; c < NPTS / 64; c += gridDim.x) {
        int p0 = c * 64;
        __syncthreads();
        if (tid < 192) sPosF[tid] = ldin(pos, p0 * 3 + tid, f32);
        __syncthreads();
#pragma unroll
        for (int ii = 0; ii < 4; ++ii) {
            int p = (tid >> 4) + 16 * ii;
            float x = sPosF[3 * p], y = sPosF[3 * p + 1], z = sPosF[3 * p + 2];
            float sx = x * mys, sy = y * mys, sz = z * mys;
            float fx = floorf(sx), fy = floorf(sy), fz = floorf(sz);
            float cx = ceilf(sx), cy = ceilf(sy), cz = ceilf(sz);
            float ox = sx - fx, oy = sy - fy, oz = sz - fz;
            uint32 hx0 = (uint32)(int)fx;
            uint32 hx1 = (uint32)(int)cx;
            uint32 hy0 = (uint32)(int)fy * 2654435761u;
            uint32 hy1 = (uint32)(int)cy * 2654435761u;
            uint32 hz0 = (uint32)(int)fz * 805459861u;
            uint32 hz1 = (uint32)(int)cz * 805459861u;
            float wx0 = 1.f - ox, wy0 = 1.f - oy, wz0 = 1.f - oz;
            float a0 = 0.f, a1 = 0.f;
#pragma unroll
            for (int cr = 0; cr < 8; ++cr) {
                uint32 h = ((cr & 1) ? hx1 : hx0) ^ ((cr & 2) ? hy1 : hy0) ^ ((cr & 4) ? hz1 : hz0);
                uint32 idx = (h & TMASK) + mybase;
                float t0, t1;
                if (f32) { float2 tv = ((const float2*)tbl)[idx]; t0 = tv.x; t1 = tv.y; }
                else { uint32 dv = ((const uint32*)tbl)[idx]; t0 = bf2f((ushort16)(dv & 0xffffu)); t1 = bf2f((ushort16)(dv >> 16)); }
                float w = ((cr & 1) ? ox : wx0) * ((cr & 2) ? oy : wy0) * ((cr & 4) ? oz : wz0);
                a0 += w * t0; a1 += w * t1;
            }
            *(uint32*)&sX[p * FSTRX + 2 * myl] = pack2(a0, a1);
        }
        __syncthreads();
        {
            short8 a = *(const short8*)&sX[(wv * 16 + colg) * FSTRX + quad * 8];
#pragma unroll
            for (int nt = 0; nt < 4; ++nt) {
                short8 bb = *(const short8*)&sW0[(nt * 16 + colg) * STRW0 + quad * 8];
                f32x4 acc = {0.f, 0.f, 0.f, 0.f};
                acc = __builtin_amdgcn_mfma_f32_16x16x32_bf16(a, bb, acc, 0, 0, 0);
                float bias = sB0[nt * 16 + colg];
#pragma unroll
                for (int r = 0; r < 4; ++r) {
                    float v = fmaxf(acc[r] + bias, 0.f);
                    sY[(wv * 16 + quad * 4 + r) * STRY + nt * 16 + colg] = f2bf(v);
                }
            }
        }
        __syncthreads();
        {
            short8 a0 = *(const short8*)&sY[(wv * 16 + colg) * STRY + quad * 8];
            short8 a1 = *(const short8*)&sY[(wv * 16 + colg) * STRY + 32 + quad * 8];
#pragma unroll
            for (int nt = 0; nt < 4; ++nt) {
                short8 bb0 = *(const short8*)&sW1[(nt * 16 + colg) * STRW12 + quad * 8];
                short8 bb1 = *(const short8*)&sW1[(nt * 16 + colg) * STRW12 + 32 + quad * 8];
                f32x4 acc = {0.f, 0.f, 0.f, 0.f};
                acc = __builtin_amdgcn_mfma_f32_16x16x32_bf16(a0, bb0, acc, 0, 0, 0);
                acc = __builtin_amdgcn_mfma_f32_16x16x32_bf16(a1, bb1, acc, 0, 0, 0);
                float bias = sB1[nt * 16 + colg];
#pragma unroll
                for (int r = 0; r < 4; ++r) {
                    float v = fmaxf(acc[r] + bias, 0.f);
                    sX[(wv * 16 + quad * 4 + r) * FSTRX + nt * 16 + colg] = f2bf(v);
                }
            }
        }
        __syncthreads();
        {
            short8 a0 = *(const short8*)&sX[(wv * 16 + colg) * FSTRX + quad * 8];
            short8 a1 = *(const short8*)&sX[(wv * 16 + colg) * FSTRX + 32 + quad * 8];
#pragma unroll
            for (int nt = 0; nt < 4; ++nt) {
                short8 bb0 = *(const short8*)&sW2[(nt * 16 + colg) * STRW12 + quad * 8];
                short8 bb1 = *(const short8*)&sW2[(nt * 16 + colg) * STRW12 + 32 + quad * 8];
                f32x4 acc = {0.f, 0.f, 0.f, 0.f};
                acc = __builtin_amdgcn_mfma_f32_16x16x32_bf16(a0, bb0, acc, 0, 0, 0);
                acc = __builtin_amdgcn_mfma_f32_16x16x32_bf16(a1, bb1, acc, 0, 0, 0);
                float bias = sB2[nt * 16 + colg];
#pragma unroll
                for (int r = 0; r < 4; ++r) {
                    sY[(wv * 16 + quad * 4 + r) * STRY + nt * 16 + colg] = f2bf(acc[r] + bias);
                }
            }
        }
        if (tid < 192) {
            int p = tid / 3, i2 = tid % 3;
            float dvv = ldin(dirs, 3 * (p0 + p) + i2, f32);
            ushort16* row = &sX[p * FSTRX + 64];
            float td = 6.28318530717958647692f * dvv;
#pragma unroll
            for (int j = 0; j < 4; ++j) {
                float arg = td * fq.f[j];
                float sv, cv;
                sincosf(arg, &sv, &cv);
                row[i2 * 4 + j] = f2bf(sv);
                row[12 + i2 * 4 + j] = f2bf(cv);
            }
            row[24 + i2] = f2bf(dvv);
        } else {
            int p = tid - 192;
            ushort16* row = &sX[p * FSTRX + 64];
#pragma unroll
            for (int j = 27; j < 32; ++j) row[j] = 0;
        }
        __syncthreads();
        {
            short8 a0 = *(const short8*)&sX[(wv * 16 + colg) * FSTRX + 64 + quad * 8];
            short8 a1 = *(const short8*)&sY[(wv * 16 + colg) * STRY + quad * 8];
            short8 a2 = *(const short8*)&sY[(wv * 16 + colg) * STRY + 32 + quad * 8];
#pragma unroll
            for (int nt = 0; nt < 2; ++nt) {
                short8 bb0 = *(const short8*)&sWR[(nt * 16 + colg) * STRWR + quad * 8];
                short8 bb1 = *(const short8*)&sWR[(nt * 16 + colg) * STRWR + 32 + quad * 8];
                short8 bb2 = *(const short8*)&sWR[(nt * 16 + colg) * STRWR + 64 + quad * 8];
                f32x4 acc = {0.f, 0.f, 0.f, 0.f};
                acc = __builtin_amdgcn_mfma_f32_16x16x32_bf16(a0, bb0, acc, 0, 0, 0);
                acc = __builtin_amdgcn_mfma_f32_16x16x32_bf16(a1, bb1, acc, 0, 0, 0);
                acc = __builtin_amdgcn_mfma_f32_16x16x32_bf16(a2, bb2, acc, 0, 0, 0);
                float bias = sBR[nt * 16 + colg];
#pragma unroll
                for (int r = 0; r < 4; ++r) {
                    sX[(wv * 16 + quad * 4 + r) * FSTRX + nt * 16 + colg] = f2bf(acc[r] + bias);
                }
            }
        }
        __syncthreads();
        if (tid < 64) {
            int pt = p0 + tid;
            float r0 = 0.f, r1 = 0.f, r2 = 0.f, dd = 0.f;
            const ushort16* hx = &sX[tid * FSTRX];
            const ushort16* hb = &sY[tid * STRY];
#pragma unroll
            for (int k = 0; k < 32; ++k) {
                float hv = bf2f(hx[k]);
                r0 += hv * sWCf[k * 3 + 0];
                r1 += hv * sWCf[k * 3 + 1];
                r2 += hv * sWCf[k * 3 + 2];
            }
#pragma unroll
            for (int k = 0; k < 64; ++k) dd += bf2f(hb[k]) * sWDf[k];
            r0 += sWCf[96]; r1 += sWCf[97]; r2 += sWCf[98]; dd += sWCf[99];
            r0 = 1.f / (1.f + expf(-r0));
            r1 = 1.f / (1.f + expf(-r1));
            r2 = 1.f / (1.f + expf(-r2));
            float sp = (dd > 0.f) ? (dd + log1pf(expf(-dd))) : log1pf(expf(dd));
            if (f32) {
                float4 o4; o4.x = r0; o4.y = r1; o4.z = r2; o4.w = sp;
                ((float4*)out)[pt] = o4;
            } else {
                uint2 o;
                o.x = pack2(r0, r1); o.y = pack2(r2, sp);
                ((uint2*)out)[pt] = o;
            }
        }
    }
}

// ---------------------------------------------------------------------------
extern "C" void kernel_launch(void* const* d_in, const int* in_sizes, int n_in,
                              void* d_out, int out_size, void* d_ws, size_t ws_size,
                              hipStream_t stream) {
    (void)in_sizes; (void)n_in; (void)out_size;

    // SCALINGS with identical libm double math to numpy
    Scal16 sc;
    double g = exp((log(1024.0) - log(16.0)) / 15.0);
    for (int l = 0; l < 16; ++l) sc.s[l] = (float)floor(16.0 * pow(g, (double)l));

    // freqs = 2 ** float32(linspace(0,4,4))
    Freq4 fq;
    float lv[4] = {0.f, 4.f / 3.f, 8.f / 3.f, 4.f};
    for (int j = 0; j < 4; ++j) fq.f[j] = (float)pow(2.0, (double)lv[j]);

    // dense grid geometry for levels 0..4 only (lvl 5 moved to hash path)
    DenseP dpp;
    HashP hp;
    dpp.pfx[0] = 0;
    for (int l = 0; l < 5; ++l) {
        int D = (int)sc.s[l] + 1;
        dpp.dD[l] = D;
        dpp.pfx[l + 1] = dpp.pfx[l] + D * D * D;
    }
    dpp.dD[5] = 1; dpp.pfx[6] = dpp.pfx[5];
    for (int l = 0; l < 16; ++l) hp.s[l] = sc.s[l];
    for (int l = 0; l < 8; ++l) {
        hp.dD[l]   = (l < 5) ? dpp.dD[l] : 1;
        hp.doff[l] = (l < 5) ? dpp.pfx[l] : 0;
    }
    int ndense = dpp.pfx[5];                              // ~205,815 entries (3.3 MB)

    const size_t enc_bytes   = (size_t)16 * NPTS * 4;     // 32 MiB packed-bf16 enc
    const size_t tbl2F_bytes = (size_t)11 * TSIZE * 4;    // 22 MiB packed-bf16 lvl 5..15
    const size_t dense_bytes = (size_t)ndense * 16 + 64;  // ~3.3 MB xy-patch entries
    const size_t need_new = enc_bytes + tbl2F_bytes + dense_bytes;   // ~57.3 MiB

    if (ws_size >= need_new) {
        uint32* enc   = (uint32*)d_ws;
        uint32* tbl2F = (uint32*)((char*)d_ws + enc_bytes);
        uint4*  dense4 = (uint4*)((char*)d_ws + enc_bytes + tbl2F_bytes);
        int nprep = 5632 + (ndense + 255) / 256;
        // one-time prep (cvt role is a no-op when input already bf16)
        k_prep<<<dim3(nprep), dim3(256), 0, stream>>>(d_in[0], d_in[2], (uint4*)tbl2F, dense4, dpp);
        // hashed levels 5..15 (XCD-balanced, channel floor)
        k_hashB<<<dim3(11 * NPTS / 256), dim3(256), 0, stream>>>(d_in[0], d_in[2], tbl2F, enc, hp);
        // mlp with fused dense gather (levels 0..4, L2-resident dense4)
        k_mlp<<<dim3(512), dim3(512), 0, stream>>>(
            d_in[0], enc, d_in[1], dense4, d_in[3], d_in[4], d_in[5], d_in[6], d_in[7],
            d_in[8], d_in[9], d_in[10], d_in[11], d_in[12], d_in[13], d_in[14],
            d_out, fq, hp, 1);
    } else if (ws_size >= enc_bytes) {
        uint32* enc = (uint32*)d_ws;
        k_hash<<<dim3(2 * 8 * NPTS / 256), dim3(256), 0, stream>>>(d_in[0], d_in[2], enc, sc);
        k_mlp<<<dim3(512), dim3(512), 0, stream>>>(
            d_in[0], enc, d_in[1], (const uint4*)d_ws /*unused*/, d_in[3], d_in[4], d_in[5], d_in[6], d_in[7],
            d_in[8], d_in[9], d_in[10], d_in[11], d_in[12], d_in[13], d_in[14],
            d_out, fq, hp, 0);
    } else {
        k_fused<<<dim3(512), dim3(256), 0, stream>>>(
            d_in[0], d_in[1], d_in[2], d_in[3], d_in[4], d_in[5], d_in[6], d_in[7],
            d_in[8], d_in[9], d_in[10], d_in[11], d_in[12], d_in[13], d_in[14],
            d_out, sc, fq);
    }
}

// Round 12
// 294.624 us; speedup vs baseline: 1.0318x; 1.0318x over previous
//
#include <hip/hip_runtime.h>
#include <math.h>

#define NPTS 524288
#define LOG2T 19
#define TSIZE (1u << LOG2T)
#define TMASK (TSIZE - 1u)

typedef unsigned int uint32;
typedef unsigned short ushort16;

typedef __attribute__((ext_vector_type(8))) short short8;
typedef __attribute__((ext_vector_type(4))) float f32x4;

__device__ __forceinline__ float bf2f(ushort16 u) {
    union { uint32 i; float f; } v; v.i = ((uint32)u) << 16; return v.f;
}
__device__ __forceinline__ ushort16 f2bf(float f) {
    union { float f; uint32 i; } v; v.f = f;
    uint32 r = v.i + 0x7fffu + ((v.i >> 16) & 1u);   // RNE
    return (ushort16)(r >> 16);
}
// Packed fp32x2 -> bf16x2 via single HW instruction (RNE, same as f2bf).
__device__ __forceinline__ uint32 pack2(float a, float b) {
    uint32 r;
    asm("v_cvt_pk_bf16_f32 %0, %1, %2" : "=v"(r) : "v"(a), "v"(b));
    return r;
}
// dtype-flexible scalar load: fp32 or bf16 per runtime flag (block-uniform)
__device__ __forceinline__ float ldin(const void* p, int i, bool f32) {
    return f32 ? ((const float*)p)[i] : bf2f(((const ushort16*)p)[i]);
}

struct Scal16 { float s[16]; };
struct Freq4  { float f[4]; };
struct HashP  { float s[16]; int dD[8]; int doff[8]; };   // dD/doff valid for lvl<6
struct DenseP { int dD[6]; int pfx[7]; };

// ---------------------------------------------------------------------------
// Dense-level interpolation from the xy-patch array (2x 16B loads). Shared by
// k_mlp's dense leg; returns packed bf16 pair.
// ---------------------------------------------------------------------------
__device__ __forceinline__ uint32 dense_interp(const uint4* __restrict__ dense4,
                                               float x, float y, float z,
                                               float s, int D, int doff) {
    float sx = x * s, sy = y * s, sz = z * s;
    float fx = floorf(sx), fy = floorf(sy), fz = floorf(sz);
    float cx = ceilf(sx), cy = ceilf(sy), cz = ceilf(sz);
    float ox = sx - fx, oy = sy - fy, oz = sz - fz;
    float wx0 = 1.f - ox, wy0 = 1.f - oy, wz0 = 1.f - oz;

    int D2 = D * D;
    int fxi = (int)fx, fyi = (int)fy, fzi = (int)fz;
    bool dxb = ((int)cx != fxi);
    bool dyb = ((int)cy != fyi);
    bool dzb = ((int)cz != fzi);
    const uint4* dp4 = dense4 + doff;
    int i0 = fxi + fyi * D + fzi * D2;
    uint4 P0 = dp4[i0];
    uint4 P1 = dp4[i0 + (dzb ? D2 : 0)];

    float a0 = 0.f, a1 = 0.f;
    {   // by=0, bz=0
        uint32 fv = P0.x, cv = dxb ? P0.y : P0.x;
        float w = wy0 * wz0;
        a0 += w * (wx0 * bf2f((ushort16)(fv & 0xffffu)) + ox * bf2f((ushort16)(cv & 0xffffu)));
        a1 += w * (wx0 * bf2f((ushort16)(fv >> 16))     + ox * bf2f((ushort16)(cv >> 16)));
    }
    {   // by=1, bz=0
        uint32 fv = dyb ? P0.z : P0.x;
        uint32 cv = dyb ? (dxb ? P0.w : P0.z) : (dxb ? P0.y : P0.x);
        float w = oy * wz0;
        a0 += w * (wx0 * bf2f((ushort16)(fv & 0xffffu)) + ox * bf2f((ushort16)(cv & 0xffffu)));
        a1 += w * (wx0 * bf2f((ushort16)(fv >> 16))     + ox * bf2f((ushort16)(cv >> 16)));
    }
    {   // by=0, bz=1
        uint32 fv = P1.x, cv = dxb ? P1.y : P1.x;
        float w = wy0 * oz;
        a0 += w * (wx0 * bf2f((ushort16)(fv & 0xffffu)) + ox * bf2f((ushort16)(cv & 0xffffu)));
        a1 += w * (wx0 * bf2f((ushort16)(fv >> 16))     + ox * bf2f((ushort16)(cv >> 16)));
    }
    {   // by=1, bz=1
        uint32 fv = dyb ? P1.z : P1.x;
        uint32 cv = dyb ? (dxb ? P1.w : P1.z) : (dxb ? P1.y : P1.x);
        float w = oy * oz;
        a0 += w * (wx0 * bf2f((ushort16)(fv & 0xffffu)) + ox * bf2f((ushort16)(cv & 0xffffu)));
        a1 += w * (wx0 * bf2f((ushort16)(fv >> 16))     + ox * bf2f((ushort16)(cv >> 16)));
    }
    return pack2(a0, a1);
}

// ---------------------------------------------------------------------------
// Kernel P: merged one-time prep.
// bid < 5120 : fp32 table -> packed-bf16 table, levels 6..15 (no-op for bf16)
// bid >= 5120: densify levels 0..5 into grid-ordered xy-patch entries
// ---------------------------------------------------------------------------
__global__ __launch_bounds__(256) void k_prep(const void* __restrict__ pos,
                                              const void* __restrict__ tbl,
                                              uint4* __restrict__ tbl2F,
                                              uint4* __restrict__ dense4,
                                              DenseP dp) {
    __shared__ int sFlag;
    int tid = threadIdx.x;
    if (tid < 64) {
        const ushort16* ph = (const ushort16*)pos;
        float v0 = bf2f(ph[tid]), v1 = bf2f(ph[tid + 64]);
        bool odd = !(fabsf(v0) <= 4.f) || !(fabsf(v1) <= 4.f);
        unsigned long long m = __ballot(odd);
        if (tid == 0) sFlag = (m != 0ull) ? 1 : 0;
    }
    __syncthreads();
    const bool f32 = (sFlag != 0);

    if (blockIdx.x < 5120) {
        if (!f32) return;
        const float4* tf4 = (const float4*)tbl;
        size_t g = (size_t)blockIdx.x * 256 + tid;   // 4 entries per thread
        float4 v0 = tf4[(size_t)3 * TSIZE + 2 * g];
        float4 v1 = tf4[(size_t)3 * TSIZE + 2 * g + 1];
        uint4 o;
        o.x = pack2(v0.x, v0.y); o.y = pack2(v0.z, v0.w);
        o.z = pack2(v1.x, v1.y); o.w = pack2(v1.z, v1.w);
        tbl2F[g] = o;
        return;
    }

    int e = (blockIdx.x - 5120) * 256 + tid;
    if (e >= dp.pfx[6]) return;
    int l = 0;
#pragma unroll
    for (int k = 1; k < 6; ++k) l += (e >= dp.pfx[k]) ? 1 : 0;
    int c = e - dp.pfx[l];
    int D = dp.dD[l], D2 = D * D;
    int cz = c / D2; int rm = c - cz * D2;
    int cy = rm / D; int cx = rm - cy * D;

    uint32 base = (uint32)l << LOG2T;
    uint32 hz  = (uint32)cz * 805459861u;
    uint32 hy0 = (uint32)cy * 2654435761u;
    uint32 hy1 = (uint32)(cy + 1) * 2654435761u;
    uint32 h00 = ((((uint32)cx)       ^ hy0 ^ hz) & TMASK) + base;
    uint32 h10 = ((((uint32)(cx + 1)) ^ hy0 ^ hz) & TMASK) + base;
    uint32 h01 = ((((uint32)cx)       ^ hy1 ^ hz) & TMASK) + base;
    uint32 h11 = ((((uint32)(cx + 1)) ^ hy1 ^ hz) & TMASK) + base;

    uint4 o;
    if (f32) {
        const float2* t2 = (const float2*)tbl;
        float2 a = t2[h00], b = t2[h10], cc = t2[h01], d = t2[h11];
        o.x = pack2(a.x, a.y); o.y = pack2(b.x, b.y);
        o.z = pack2(cc.x, cc.y); o.w = pack2(d.x, d.y);
    } else {
        const uint32* t1 = (const uint32*)tbl;
        o.x = t1[h00]; o.y = t1[h10]; o.z = t1[h01]; o.w = t1[h11];
    }
    dense4[e] = o;
}

// ---------------------------------------------------------------------------
// Kernel F: balanced hashed encode, levels 6..15 in ONE dispatch (measured
// 98 us @ 17.2 lines/cy/XCD = channel floor). XCD k (= bid&7) gets 1.25
// levels of contiguous (lvl,chunk) work -> <=2 table slices = L2-resident.
// Levels 0..5 are NOT written here (k_mlp computes them from dense4).
// ---------------------------------------------------------------------------
__global__ __launch_bounds__(256) void k_hashB(const void* __restrict__ pos,
                                               const void* __restrict__ tbl,
                                               const uint32* __restrict__ tbl2F,
                                               uint32* __restrict__ enc,
                                               HashP hp) {
    __shared__ __align__(16) uint4 sPosQ[192];
    __shared__ int sFlag;
    int tid = threadIdx.x;
    if (tid < 64) {
        const ushort16* ph = (const ushort16*)pos;
        float v0 = bf2f(ph[tid]), v1 = bf2f(ph[tid + 64]);
        bool odd = !(fabsf(v0) <= 4.f) || !(fabsf(v1) <= 4.f);
        unsigned long long m = __ballot(odd);
        if (tid == 0) sFlag = (m != 0ull) ? 1 : 0;
    }
    __syncthreads();
    const bool f32 = (sFlag != 0);

    int xcd = blockIdx.x & 7;
    int slot = blockIdx.x >> 3;               // [0, 2560)
    int W = xcd * 2560 + slot;                // [0, 20480)
    int lvl = 6 + (W >> 11);                  // 6..15
    int chunk = W & 2047;
    int p0 = chunk * 256;
    int pt = p0 + tid;

    {
        int n16 = f32 ? 192 : 96;
        const uint4* src = (const uint4*)((const char*)pos + (size_t)p0 * (f32 ? 12 : 6));
        for (int i = tid; i < n16; i += 256) sPosQ[i] = src[i];
    }
    __syncthreads();

    float x, y, z;
    if (f32) {
        const float* pf = (const float*)sPosQ;
        x = pf[3 * tid]; y = pf[3 * tid + 1]; z = pf[3 * tid + 2];
    } else {
        const ushort16* ph2 = (const ushort16*)sPosQ;
        x = bf2f(ph2[3 * tid]); y = bf2f(ph2[3 * tid + 1]); z = bf2f(ph2[3 * tid + 2]);
    }

    float s = hp.s[lvl];
    float sx = x * s, sy = y * s, sz = z * s;
    float fx = floorf(sx), fy = floorf(sy), fz = floorf(sz);
    float cx = ceilf(sx), cy = ceilf(sy), cz = ceilf(sz);   // ceil, NOT floor+1 (matches ref)
    float ox = sx - fx, oy = sy - fy, oz = sz - fz;
    float wx0 = 1.f - ox, wy0 = 1.f - oy, wz0 = 1.f - oz;

    const uint32* tp; uint32 base;
    if (f32) { tp = tbl2F; base = (uint32)(lvl - 6) << LOG2T; }
    else     { tp = (const uint32*)tbl; base = (uint32)lvl << LOG2T; }
    uint32 hx0 = (uint32)(int)fx;                       // prime[0] = 1
    uint32 hx1 = (uint32)(int)cx;
    uint32 hy0 = (uint32)(int)fy * 2654435761u;
    uint32 hy1 = (uint32)(int)cy * 2654435761u;
    uint32 hz0 = (uint32)(int)fz * 805459861u;
    uint32 hz1 = (uint32)(int)cz * 805459861u;

    float a0 = 0.f, a1 = 0.f;
#pragma unroll
    for (int yz = 0; yz < 4; ++yz) {
        uint32 m = ((yz & 1) ? hy1 : hy0) ^ ((yz & 2) ? hz1 : hz0);
        float wyz = ((yz & 1) ? oy : wy0) * ((yz & 2) ? oz : wz0);
        uint32 i0 = ((hx0 ^ m) & TMASK) + base;
        uint32 i1 = ((hx1 ^ m) & TMASK) + base;
        uint32 d0, d1;
        if (i1 == (i0 ^ 1u)) {              // even-fx pair: one 8 B load
            uint2 pv = *(const uint2*)(tp + (i0 & ~1u));
            d0 = (i0 & 1u) ? pv.y : pv.x;
            d1 = (i0 & 1u) ? pv.x : pv.y;
        } else {                            // unpaired: two 4 B loads
            d0 = tp[i0]; d1 = tp[i1];
        }
        a0 += wyz * (wx0 * bf2f((ushort16)(d0 & 0xffffu)) + ox * bf2f((ushort16)(d1 & 0xffffu)));
        a1 += wyz * (wx0 * bf2f((ushort16)(d0 >> 16))     + ox * bf2f((ushort16)(d1 >> 16)));
    }
    enc[(size_t)lvl * NPTS + pt] = pack2(a0, a1);
}

// ---------------------------------------------------------------------------
// LEGACY Kernel A (fallback when ws too small): level-major hash encode,
// writes ALL 16 levels (fallback k_mlp stages them all; denseMode=0).
// ---------------------------------------------------------------------------
__global__ __launch_bounds__(256) void k_hash(const void* __restrict__ pos,
                                              const void* __restrict__ tbl,
                                              uint32* __restrict__ enc,
                                              Scal16 sc) {
    __shared__ int sFlag;
    int tid = threadIdx.x;
    if (tid < 64) {
        const ushort16* ph = (const ushort16*)pos;
        float v0 = bf2f(ph[tid]), v1 = bf2f(ph[tid + 64]);
        bool odd = !(fabsf(v0) <= 4.f) || !(fabsf(v1) <= 4.f);
        unsigned long long m = __ballot(odd);
        if (tid == 0) sFlag = (m != 0ull) ? 1 : 0;
    }
    __syncthreads();
    const bool f32 = (sFlag != 0);

    int lvl = ((blockIdx.x >> 14) << 3) + (blockIdx.x & 7);
    int pt = ((blockIdx.x >> 3) & 2047) * 256 + tid;

    float s = sc.s[lvl];
    float x = ldin(pos, 3 * pt, f32), y = ldin(pos, 3 * pt + 1, f32), z = ldin(pos, 3 * pt + 2, f32);
    float sx = x * s, sy = y * s, sz = z * s;
    float fx = floorf(sx), fy = floorf(sy), fz = floorf(sz);
    float cx = ceilf(sx), cy = ceilf(sy), cz = ceilf(sz);
    float ox = sx - fx, oy = sy - fy, oz = sz - fz;
    uint32 hx0 = (uint32)(int)fx;
    uint32 hx1 = (uint32)(int)cx;
    uint32 hy0 = (uint32)(int)fy * 2654435761u;
    uint32 hy1 = (uint32)(int)cy * 2654435761u;
    uint32 hz0 = (uint32)(int)fz * 805459861u;
    uint32 hz1 = (uint32)(int)cz * 805459861u;
    uint32 base = (uint32)lvl << LOG2T;
    float wx0 = 1.f - ox, wy0 = 1.f - oy, wz0 = 1.f - oz;

    float a0 = 0.f, a1 = 0.f;
    if (f32) {
        const float* tf = (const float*)tbl;
#pragma unroll
        for (int yz = 0; yz < 4; ++yz) {
            uint32 m = ((yz & 1) ? hy1 : hy0) ^ ((yz & 2) ? hz1 : hz0);
            float wyz = ((yz & 1) ? oy : wy0) * ((yz & 2) ? oz : wz0);
            uint32 i0 = ((hx0 ^ m) & TMASK) + base;
            uint32 i1 = ((hx1 ^ m) & TMASK) + base;
            float4 pv = *(const float4*)(tf + (size_t)(i0 & ~1u) * 2);
            bool lo = !(i0 & 1u);
            float f0 = lo ? pv.x : pv.z, f1 = lo ? pv.y : pv.w;
            float c0, c1;
            if (i1 == (i0 ^ 1u)) { c0 = lo ? pv.z : pv.x; c1 = lo ? pv.w : pv.y; }
            else { float2 tv = ((const float2*)tbl)[i1]; c0 = tv.x; c1 = tv.y; }
            a0 += wyz * (wx0 * f0 + ox * c0);
            a1 += wyz * (wx0 * f1 + ox * c1);
        }
    } else {
#pragma unroll
        for (int cr = 0; cr < 8; ++cr) {
            uint32 h = ((cr & 1) ? hx1 : hx0) ^ ((cr & 2) ? hy1 : hy0) ^ ((cr & 4) ? hz1 : hz0);
            uint32 idx = (h & TMASK) + base;
            uint32 dv = ((const uint32*)tbl)[idx];
            float w = ((cr & 1) ? ox : wx0) * ((cr & 2) ? oy : wy0) * ((cr & 4) ? oz : wz0);
            a0 += w * bf2f((ushort16)(dv & 0xffffu));
            a1 += w * bf2f((ushort16)(dv >> 16));
        }
    }
    enc[(size_t)lvl * NPTS + pt] = pack2(a0, a1);
}

// ---------------------------------------------------------------------------
// Kernel B: R8 structure, round-8 BEST-MEASURED configuration (297.6 us):
// dense levels 0..5 computed in the staging phase by waves 0-1 (own-point,
// 6 interps each) while waves 2-7 do dir encode + hashed staging. R9-R11
// variants (balanced jobs, LDS pos, level-5-to-hash) all measured neutral
// or worse; this split is the measured optimum (dense ~4.4 us/lvl in-mlp
// vs 9.85 us/lvl hashed).
// denseMode=0 restores the legacy full-stage path (fallback).
// ---------------------------------------------------------------------------
#define STRY 76
#define STRW0 40
#define STRW12 76
#define STRWR 104
#define MSTRX 100
#define PPI 128                 // points per iteration
#define NIT (NPTS / PPI)

__global__ __launch_bounds__(512) void k_mlp(
    const void* __restrict__ pos,   // dtype detection + dense-leg pos loads
    const uint32* __restrict__ enc, const void* __restrict__ dirs,
    const uint4* __restrict__ dense4,
    const void* __restrict__ w0, const void* __restrict__ b0,
    const void* __restrict__ w1, const void* __restrict__ b1,
    const void* __restrict__ w2, const void* __restrict__ b2,
    const void* __restrict__ wr, const void* __restrict__ br,
    const void* __restrict__ wc, const void* __restrict__ bc,
    const void* __restrict__ wd, const void* __restrict__ bd,
    void* __restrict__ out, Freq4 fq, HashP hp, int denseMode)
{
    __shared__ __align__(16) ushort16 sX[PPI * MSTRX];
    __shared__ __align__(16) ushort16 sY[PPI * STRY];
    __shared__ __align__(16) ushort16 sW0[64 * STRW0];
    __shared__ __align__(16) ushort16 sW1[64 * STRW12];
    __shared__ __align__(16) ushort16 sW2[64 * STRW12];
    __shared__ __align__(16) ushort16 sWR[32 * STRWR];
    __shared__ __align__(16) ushort16 sW4[16 * STRWR];
    __shared__ __align__(16) float sB0[64], sB1[64], sB2[64], sBR[32], sFB[4];
    __shared__ int sFlag;

    int tid = threadIdx.x;

    if (tid < 64) {
        const ushort16* ph = (const ushort16*)pos;
        float v0 = bf2f(ph[tid]), v1 = bf2f(ph[tid + 64]);
        bool odd = !(fabsf(v0) <= 4.f) || !(fabsf(v1) <= 4.f);
        unsigned long long m = __ballot(odd);
        if (tid == 0) sFlag = (m != 0ull) ? 1 : 0;
    }
    __syncthreads();
    const bool f32 = (sFlag != 0);

    // ---- stage weights once (transpose to [n][k], bf16) ----
    for (int i = tid; i < 2048; i += 512) { int k = i >> 6, n = i & 63; sW0[n * STRW0 + k] = f2bf(ldin(w0, i, f32)); }
    for (int i = tid; i < 4096; i += 512) { int k = i >> 6, n = i & 63; sW1[n * STRW12 + k] = f2bf(ldin(w1, i, f32)); }
    for (int i = tid; i < 4096; i += 512) { int k = i >> 6, n = i & 63; sW2[n * STRW12 + k] = f2bf(ldin(w2, i, f32)); }
    // wr[91][32]: rows 0..26 (dir) -> k=r; rows 27..90 (base) -> k=r+5
    for (int i = tid; i < 2912; i += 512) {
        int r = i >> 5, n = i & 31; int k = (r < 27) ? r : r + 5;
        sWR[n * STRWR + k] = f2bf(ldin(wr, i, f32));
    }
    if (tid < 160) { int n = tid / 5, k = 27 + tid % 5; sWR[n * STRWR + k] = 0; }  // zero pad k=27..31
    // W4[16][96]: k 0..63 = base, k 64..95 = rgb_h; rows 0..2 = wc, row 3 = wd
    for (int i = tid; i < 1536; i += 512) {
        int n = i / 96, j = i % 96;
        float v = 0.f;
        if (n == 3 && j < 64) v = ldin(wd, j, f32);
        else if (n < 3 && j >= 64) v = ldin(wc, (j - 64) * 3 + n, f32);
        sW4[n * STRWR + j] = f2bf(v);
    }
    if (tid < 64) { sB0[tid] = ldin(b0, tid, f32); sB1[tid] = ldin(b1, tid, f32); sB2[tid] = ldin(b2, tid, f32); }
    if (tid < 32) sBR[tid] = ldin(br, tid, f32);
    if (tid < 3) sFB[tid] = ldin(bc, tid, f32);
    if (tid == 3) sFB[3] = ldin(bd, 0, f32);

    int lane = tid & 63, wv = tid >> 6;          // wv in [0,8)
    int colg = lane & 15, quad = lane >> 4;
    int myrow = wv * 16 + colg;                  // this lane's point row in [0,128)

    for (int c = blockIdx.x; c < NIT; c += gridDim.x) {
        int p0 = c * PPI;
        __syncthreads();   // B1: prev iteration finale reads done (covers weight staging on iter 0)

        if (denseMode) {
            // ---- waves 0-1: this thread's point -> 6 dense levels + zero pad ----
            if (tid < 128) {
                int pt = p0 + tid;
                float x, y, z;
                if (f32) {
                    const float* pf = (const float*)pos;
                    x = pf[3 * pt]; y = pf[3 * pt + 1]; z = pf[3 * pt + 2];
                } else {
                    const ushort16* ph2 = (const ushort16*)pos;
                    x = bf2f(ph2[3 * pt]); y = bf2f(ph2[3 * pt + 1]); z = bf2f(ph2[3 * pt + 2]);
                }
                ushort16* row = &sX[tid * MSTRX];
#pragma unroll
                for (int l = 0; l < 6; ++l) {
                    *(uint32*)&row[2 * l] = dense_interp(dense4, x, y, z, hp.s[l], hp.dD[l], hp.doff[l]);
                }
#pragma unroll
                for (int j = 27; j < 32; ++j) row[64 + j] = 0;   // cols 91..95
            } else {
                int t = tid - 128;   // 0..383
                // ---- dir encode (one component per thread, 384 = 128x3) ----
                {
                    int p = t / 3, i2 = t - 3 * (t / 3);
                    float dvv = ldin(dirs, 3 * (p0 + p) + i2, f32);
                    ushort16* row = &sX[p * MSTRX + 64];
                    float td = 6.28318530717958647692f * dvv;
                    float a0 = td * fq.f[0], a1 = td * fq.f[1], a2 = td * fq.f[2], a3 = td * fq.f[3];
                    uint2 sv, cv;
                    sv.x = pack2(__sinf(a0), __sinf(a1));
                    sv.y = pack2(__sinf(a2), __sinf(a3));
                    cv.x = pack2(__cosf(a0), __cosf(a1));
                    cv.y = pack2(__cosf(a2), __cosf(a3));
                    *(uint2*)&row[i2 * 4] = sv;
                    *(uint2*)&row[12 + i2 * 4] = cv;
                    row[24 + i2] = f2bf(dvv);
                }
                // ---- stage hashed levels 6..15 -> sX cols 12..31 (640 jobs) ----
                for (int i = t; i < 640; i += 384) {
                    int l = i % 10; int pp = (i / 10) * 2;
                    uint2 e = *(const uint2*)&enc[(size_t)(6 + l) * NPTS + p0 + pp];
                    *(uint32*)&sX[pp * MSTRX + 12 + 2 * l] = e.x;
                    *(uint32*)&sX[(pp + 1) * MSTRX + 12 + 2 * l] = e.y;
                }
            }
        } else {
            // ---- legacy: stage all 16 levels from enc ----
            for (int i = tid; i < 1024; i += 512) {
                int l = i & 15, pp = (i >> 4) * 2;
                uint2 e = *(const uint2*)&enc[(size_t)l * NPTS + p0 + pp];
                *(uint32*)&sX[pp * MSTRX + 2 * l] = e.x;
                *(uint32*)&sX[(pp + 1) * MSTRX + 2 * l] = e.y;
            }
            if (tid < 384) {
                int p = tid / 3, i2 = tid - 3 * (tid / 3);
                float dvv = ldin(dirs, 3 * (p0 + p) + i2, f32);
                ushort16* row = &sX[p * MSTRX + 64];
                float td = 6.28318530717958647692f * dvv;
                float a0 = td * fq.f[0], a1 = td * fq.f[1], a2 = td * fq.f[2], a3 = td * fq.f[3];
                uint2 sv, cv;
                sv.x = pack2(__sinf(a0), __sinf(a1));
                sv.y = pack2(__sinf(a2), __sinf(a3));
                cv.x = pack2(__cosf(a0), __cosf(a1));
                cv.y = pack2(__cosf(a2), __cosf(a3));
                *(uint2*)&row[i2 * 4] = sv;
                *(uint2*)&row[12 + i2 * 4] = cv;
                row[24 + i2] = f2bf(dvv);
            } else {
                int p = tid - 384;
                ushort16* row = &sX[p * MSTRX + 64];
#pragma unroll
                for (int j = 27; j < 32; ++j) row[j] = 0;
            }
        }
        __syncthreads();   // B2: enc + dir staged

        // ---- L0: relu(enc @ w0 + b0) -> sY[0..63] (operand-swapped, packed WB) ----
        {
            short8 xb = *(const short8*)&sX[myrow * MSTRX + quad * 8];
#pragma unroll
            for (int nt = 0; nt < 4; ++nt) {
                short8 a = *(const short8*)&sW0[(nt * 16 + colg) * STRW0 + quad * 8];
                f32x4 acc = {0.f, 0.f, 0.f, 0.f};
                acc = __builtin_amdgcn_mfma_f32_16x16x32_bf16(a, xb, acc, 0, 0, 0);
                float4 bi = *(const float4*)&sB0[nt * 16 + quad * 4];
                uint2 o;
                o.x = pack2(fmaxf(acc[0] + bi.x, 0.f), fmaxf(acc[1] + bi.y, 0.f));
                o.y = pack2(fmaxf(acc[2] + bi.z, 0.f), fmaxf(acc[3] + bi.w, 0.f));
                *(uint2*)&sY[myrow * STRY + nt * 16 + quad * 4] = o;
            }
        }
        // ---- L1: relu(h0 @ w1 + b1) -> sX[0..63] ----
        {
            short8 xb0 = *(const short8*)&sY[myrow * STRY + quad * 8];
            short8 xb1 = *(const short8*)&sY[myrow * STRY + 32 + quad * 8];
#pragma unroll
            for (int nt = 0; nt < 4; ++nt) {
                short8 a0 = *(const short8*)&sW1[(nt * 16 + colg) * STRW12 + quad * 8];
                short8 a1 = *(const short8*)&sW1[(nt * 16 + colg) * STRW12 + 32 + quad * 8];
                f32x4 acc = {0.f, 0.f, 0.f, 0.f};
                acc = __builtin_amdgcn_mfma_f32_16x16x32_bf16(a0, xb0, acc, 0, 0, 0);
                acc = __builtin_amdgcn_mfma_f32_16x16x32_bf16(a1, xb1, acc, 0, 0, 0);
                float4 bi = *(const float4*)&sB1[nt * 16 + quad * 4];
                uint2 o;
                o.x = pack2(fmaxf(acc[0] + bi.x, 0.f), fmaxf(acc[1] + bi.y, 0.f));
                o.y = pack2(fmaxf(acc[2] + bi.z, 0.f), fmaxf(acc[3] + bi.w, 0.f));
                *(uint2*)&sX[myrow * MSTRX + nt * 16 + quad * 4] = o;
            }
        }
        // ---- L2: base = h1 @ w2 + b2 -> sY[0..63] (linear) ----
        {
            short8 xb0 = *(const short8*)&sX[myrow * MSTRX + quad * 8];
            short8 xb1 = *(const short8*)&sX[myrow * MSTRX + 32 + quad * 8];
#pragma unroll
            for (int nt = 0; nt < 4; ++nt) {
                short8 a0 = *(const short8*)&sW2[(nt * 16 + colg) * STRW12 + quad * 8];
                short8 a1 = *(const short8*)&sW2[(nt * 16 + colg) * STRW12 + 32 + quad * 8];
                f32x4 acc = {0.f, 0.f, 0.f, 0.f};
                acc = __builtin_amdgcn_mfma_f32_16x16x32_bf16(a0, xb0, acc, 0, 0, 0);
                acc = __builtin_amdgcn_mfma_f32_16x16x32_bf16(a1, xb1, acc, 0, 0, 0);
                float4 bi = *(const float4*)&sB2[nt * 16 + quad * 4];
                uint2 o;
                o.x = pack2(acc[0] + bi.x, acc[1] + bi.y);
                o.y = pack2(acc[2] + bi.z, acc[3] + bi.w);
                *(uint2*)&sY[myrow * STRY + nt * 16 + quad * 4] = o;
            }
        }
        // ---- Lr: rgb_h = [dir|base] @ wr + br -> sX[0..31] (K=96) ----
        {
            short8 xb0 = *(const short8*)&sX[myrow * MSTRX + 64 + quad * 8];
            short8 xb1 = *(const short8*)&sY[myrow * STRY + quad * 8];
            short8 xb2 = *(const short8*)&sY[myrow * STRY + 32 + quad * 8];
#pragma unroll
            for (int nt = 0; nt < 2; ++nt) {
                short8 a0 = *(const short8*)&sWR[(nt * 16 + colg) * STRWR + quad * 8];
                short8 a1 = *(const short8*)&sWR[(nt * 16 + colg) * STRWR + 32 + quad * 8];
                short8 a2 = *(const short8*)&sWR[(nt * 16 + colg) * STRWR + 64 + quad * 8];
                f32x4 acc = {0.f, 0.f, 0.f, 0.f};
                acc = __builtin_amdgcn_mfma_f32_16x16x32_bf16(a0, xb0, acc, 0, 0, 0);
                acc = __builtin_amdgcn_mfma_f32_16x16x32_bf16(a1, xb1, acc, 0, 0, 0);
                acc = __builtin_amdgcn_mfma_f32_16x16x32_bf16(a2, xb2, acc, 0, 0, 0);
                float4 bi = *(const float4*)&sBR[nt * 16 + quad * 4];
                uint2 o;
                o.x = pack2(acc[0] + bi.x, acc[1] + bi.y);
                o.y = pack2(acc[2] + bi.z, acc[3] + bi.w);
                *(uint2*)&sX[myrow * MSTRX + nt * 16 + quad * 4] = o;
            }
        }
        // ---- finale: D' = W4 @ [base|rgb_h]^T; quad0 lane holds (r,g,b,dd) ----
        {
            short8 xb0 = *(const short8*)&sY[myrow * STRY + quad * 8];        // base 0..31
            short8 xb1 = *(const short8*)&sY[myrow * STRY + 32 + quad * 8];   // base 32..63
            short8 xb2 = *(const short8*)&sX[myrow * MSTRX + quad * 8];       // rgb_h 0..31
            short8 a0 = *(const short8*)&sW4[colg * STRWR + quad * 8];
            short8 a1 = *(const short8*)&sW4[colg * STRWR + 32 + quad * 8];
            short8 a2 = *(const short8*)&sW4[colg * STRWR + 64 + quad * 8];
            f32x4 acc = {0.f, 0.f, 0.f, 0.f};
            acc = __builtin_amdgcn_mfma_f32_16x16x32_bf16(a0, xb0, acc, 0, 0, 0);
            acc = __builtin_amdgcn_mfma_f32_16x16x32_bf16(a1, xb1, acc, 0, 0, 0);
            acc = __builtin_amdgcn_mfma_f32_16x16x32_bf16(a2, xb2, acc, 0, 0, 0);
            if (quad == 0) {
                float r0 = acc[0] + sFB[0], r1 = acc[1] + sFB[1], r2 = acc[2] + sFB[2], dd = acc[3] + sFB[3];
                r0 = 1.f / (1.f + expf(-r0));
                r1 = 1.f / (1.f + expf(-r1));
                r2 = 1.f / (1.f + expf(-r2));
                float sp = (dd > 0.f) ? (dd + log1pf(expf(-dd))) : log1pf(expf(dd));
                int pt = p0 + myrow;
                if (f32) {
                    float4 o4; o4.x = r0; o4.y = r1; o4.z = r2; o4.w = sp;
                    ((float4*)out)[pt] = o4;
                } else {
                    uint2 o; o.x = pack2(r0, r1); o.y = pack2(r2, sp);
                    ((uint2*)out)[pt] = o;
                }
            }
        }
        // no B3: finale reads only own-wave rows; B1 protects next staging
    }
}

// ---------------------------------------------------------------------------
// Fallback: the round-3 PASSING fully fused kernel (used if ws too small).
// ---------------------------------------------------------------------------
#define FSTRX 104
__global__ __launch_bounds__(256) void k_fused(
    const void* __restrict__ pos, const void* __restrict__ dirs,
    const void* __restrict__ tbl,
    const void* __restrict__ w0, const void* __restrict__ b0,
    const void* __restrict__ w1, const void* __restrict__ b1,
    const void* __restrict__ w2, const void* __restrict__ b2,
    const void* __restrict__ wr, const void* __restrict__ br,
    const void* __restrict__ wc, const void* __restrict__ bc,
    const void* __restrict__ wd, const void* __restrict__ bd,
    void* __restrict__ out, Scal16 sc, Freq4 fq)
{
    __shared__ __align__(16) ushort16 sX[64 * FSTRX];
    __shared__ __align__(16) ushort16 sY[64 * STRY];
    __shared__ __align__(16) ushort16 sW0[64 * STRW0];
    __shared__ __align__(16) ushort16 sW1[64 * STRW12];
    __shared__ __align__(16) ushort16 sW2[64 * STRW12];
    __shared__ __align__(16) ushort16 sWR[32 * STRWR];
    __shared__ float sB0[64], sB1[64], sB2[64], sBR[32];
    __shared__ float sWCf[100];
    __shared__ float sWDf[64];
    __shared__ float sPosF[192];
    __shared__ int sFlag;

    int tid = threadIdx.x;
    if (tid < 64) {
        const ushort16* ph = (const ushort16*)pos;
        float v0 = bf2f(ph[tid]), v1 = bf2f(ph[tid + 64]);
        bool odd = !(fabsf(v0) <= 4.f) || !(fabsf(v1) <= 4.f);
        unsigned long long m = __ballot(odd);
        if (tid == 0) sFlag = (m != 0ull) ? 1 : 0;
    }
    __syncthreads();
    const bool f32 = (sFlag != 0);

    for (int i = tid; i < 2048; i += 256) { int k = i >> 6, n = i & 63; sW0[n * STRW0 + k] = f2bf(ldin(w0, i, f32)); }
    for (int i = tid; i < 4096; i += 256) { int k = i >> 6, n = i & 63; sW1[n * STRW12 + k] = f2bf(ldin(w1, i, f32)); }
    for (int i = tid; i < 4096; i += 256) { int k = i >> 6, n = i & 63; sW2[n * STRW12 + k] = f2bf(ldin(w2, i, f32)); }
    for (int i = tid; i < 2912; i += 256) {
        int r = i >> 5, n = i & 31; int k = (r < 27) ? r : r + 5;
        sWR[n * STRWR + k] = f2bf(ldin(wr, i, f32));
    }
    if (tid < 160) { int n = tid / 5, k = 27 + tid % 5; sWR[n * STRWR + k] = 0; }
    if (tid < 64) { sB0[tid] = ldin(b0, tid, f32); sB1[tid] = ldin(b1, tid, f32);
                    sB2[tid] = ldin(b2, tid, f32); sWDf[tid] = ldin(wd, tid, f32); }
    if (tid < 32) sBR[tid] = ldin(br, tid, f32);
    if (tid < 96) sWCf[tid] = ldin(wc, tid, f32);
    if (tid == 96) { sWCf[96] = ldin(bc, 0, f32); sWCf[97] = ldin(bc, 1, f32);
                     sWCf[98] = ldin(bc, 2, f32); sWCf[99] = ldin(bd, 0, f32); }

    int lane = tid & 63, wv = tid >> 6;
    int colg = lane & 15, quad = lane >> 4;
    int myl = tid & 15;
    float mys = sc.s[myl];
    uint32 mybase = (uint32)myl << LOG2T;

    for (int c = blockIdx.x; c < NPTS / 64; c += gridDim.x) {
        int p0 = c * 64;
        __syncthreads();
        if (tid < 192) sPosF[tid] = ldin(pos, p0 * 3 + tid, f32);
        __syncthreads();
#pragma unroll
        for (int ii = 0; ii < 4; ++ii) {
            int p = (tid >> 4) + 16 * ii;
            float x = sPosF[3 * p], y = sPosF[3 * p + 1], z = sPosF[3 * p + 2];
            float sx = x * mys, sy = y * mys, sz = z * mys;
            float fx = floorf(sx), fy = floorf(sy), fz = floorf(sz);
            float cx = ceilf(sx), cy = ceilf(sy), cz = ceilf(sz);
            float ox = sx - fx, oy = sy - fy, oz = sz - fz;
            uint32 hx0 = (uint32)(int)fx;
            uint32 hx1 = (uint32)(int)cx;
            uint32 hy0 = (uint32)(int)fy * 2654435761u;
            uint32 hy1 = (uint32)(int)cy * 2654435761u;
            uint32 hz0 = (uint32)(int)fz * 805459861u;
            uint32 hz1 = (uint32)(int)cz * 805459861u;
            float wx0 = 1.f - ox, wy0 = 1.f - oy, wz0 = 1.f - oz;
            float a0 = 0.f, a1 = 0.f;
#pragma unroll
            for (int cr = 0; cr < 8; ++cr) {
                uint32 h = ((cr & 1) ? hx1 : hx0) ^ ((cr & 2) ? hy1 : hy0) ^ ((cr & 4) ? hz1 : hz0);
                uint32 idx = (h & TMASK) + mybase;
                float t0, t1;
                if (f32) { float2 tv = ((const float2*)tbl)[idx]; t0 = tv.x; t1 = tv.y; }
                else { uint32 dv = ((const uint32*)tbl)[idx]; t0 = bf2f((ushort16)(dv & 0xffffu)); t1 = bf2f((ushort16)(dv >> 16)); }
                float w = ((cr & 1) ? ox : wx0) * ((cr & 2) ? oy : wy0) * ((cr & 4) ? oz : wz0);
                a0 += w * t0; a1 += w * t1;
            }
            *(uint32*)&sX[p * FSTRX + 2 * myl] = pack2(a0, a1);
        }
        __syncthreads();
        {
            short8 a = *(const short8*)&sX[(wv * 16 + colg) * FSTRX + quad * 8];
#pragma unroll
            for (int nt = 0; nt < 4; ++nt) {
                short8 bb = *(const short8*)&sW0[(nt * 16 + colg) * STRW0 + quad * 8];
                f32x4 acc = {0.f, 0.f, 0.f, 0.f};
                acc = __builtin_amdgcn_mfma_f32_16x16x32_bf16(a, bb, acc, 0, 0, 0);
                float bias = sB0[nt * 16 + colg];
#pragma unroll
                for (int r = 0; r < 4; ++r) {
                    float v = fmaxf(acc[r] + bias, 0.f);
                    sY[(wv * 16 + quad * 4 + r) * STRY + nt * 16 + colg] = f2bf(v);
                }
            }
        }
        __syncthreads();
        {
            short8 a0 = *(const short8*)&sY[(wv * 16 + colg) * STRY + quad * 8];
            short8 a1 = *(const short8*)&sY[(wv * 16 + colg) * STRY + 32 + quad * 8];
#pragma unroll
            for (int nt = 0; nt < 4; ++nt) {
                short8 bb0 = *(const short8*)&sW1[(nt * 16 + colg) * STRW12 + quad * 8];
                short8 bb1 = *(const short8*)&sW1[(nt * 16 + colg) * STRW12 + 32 + quad * 8];
                f32x4 acc = {0.f, 0.f, 0.f, 0.f};
                acc = __builtin_amdgcn_mfma_f32_16x16x32_bf16(a0, bb0, acc, 0, 0, 0);
                acc = __builtin_amdgcn_mfma_f32_16x16x32_bf16(a1, bb1, acc, 0, 0, 0);
                float bias = sB1[nt * 16 + colg];
#pragma unroll
                for (int r = 0; r < 4; ++r) {
                    float v = fmaxf(acc[r] + bias, 0.f);
                    sX[(wv * 16 + quad * 4 + r) * FSTRX + nt * 16 + colg] = f2bf(v);
                }
            }
        }
        __syncthreads();
        {
            short8 a0 = *(const short8*)&sX[(wv * 16 + colg) * FSTRX + quad * 8];
            short8 a1 = *(const short8*)&sX[(wv * 16 + colg) * FSTRX + 32 + quad * 8];
#pragma unroll
            for (int nt = 0; nt < 4; ++nt) {
                short8 bb0 = *(const short8*)&sW2[(nt * 16 + colg) * STRW12 + quad * 8];
                short8 bb1 = *(const short8*)&sW2[(nt * 16 + colg) * STRW12 + 32 + quad * 8];
                f32x4 acc = {0.f, 0.f, 0.f, 0.f};
                acc = __builtin_amdgcn_mfma_f32_16x16x32_bf16(a0, bb0, acc, 0, 0, 0);
                acc = __builtin_amdgcn_mfma_f32_16x16x32_bf16(a1, bb1, acc, 0, 0, 0);
                float bias = sB2[nt * 16 + colg];
#pragma unroll
                for (int r = 0; r < 4; ++r) {
                    sY[(wv * 16 + quad * 4 + r) * STRY + nt * 16 + colg] = f2bf(acc[r] + bias);
                }
            }
        }
        if (tid < 192) {
            int p = tid / 3, i2 = tid % 3;
            float dvv = ldin(dirs, 3 * (p0 + p) + i2, f32);
            ushort16* row = &sX[p * FSTRX + 64];
            float td = 6.28318530717958647692f * dvv;
#pragma unroll
            for (int j = 0; j < 4; ++j) {
                float arg = td * fq.f[j];
                float sv, cv;
                sincosf(arg, &sv, &cv);
                row[i2 * 4 + j] = f2bf(sv);
                row[12 + i2 * 4 + j] = f2bf(cv);
            }
            row[24 + i2] = f2bf(dvv);
        } else {
            int p = tid - 192;
            ushort16* row = &sX[p * FSTRX + 64];
#pragma unroll
            for (int j = 27; j < 32; ++j) row[j] = 0;
        }
        __syncthreads();
        {
            short8 a0 = *(const short8*)&sX[(wv * 16 + colg) * FSTRX + 64 + quad * 8];
            short8 a1 = *(const short8*)&sY[(wv * 16 + colg) * STRY + quad * 8];
            short8 a2 = *(const short8*)&sY[(wv * 16 + colg) * STRY + 32 + quad * 8];
#pragma unroll
            for (int nt = 0; nt < 2; ++nt) {
                short8 bb0 = *(const short8*)&sWR[(nt * 16 + colg) * STRWR + quad * 8];
                short8 bb1 = *(const short8*)&sWR[(nt * 16 + colg) * STRWR + 32 + quad * 8];
                short8 bb2 = *(const short8*)&sWR[(nt * 16 + colg) * STRWR + 64 + quad * 8];
                f32x4 acc = {0.f, 0.f, 0.f, 0.f};
                acc = __builtin_amdgcn_mfma_f32_16x16x32_bf16(a0, bb0, acc, 0, 0, 0);
                acc = __builtin_amdgcn_mfma_f32_16x16x32_bf16(a1, bb1, acc, 0, 0, 0);
                acc = __builtin_amdgcn_mfma_f32_16x16x32_bf16(a2, bb2, acc, 0, 0, 0);
                float bias = sBR[nt * 16 + colg];
#pragma unroll
                for (int r = 0; r < 4; ++r) {
                    sX[(wv * 16 + quad * 4 + r) * FSTRX + nt * 16 + colg] = f2bf(acc[r] + bias);
                }
            }
        }
        __syncthreads();
        if (tid < 64) {
            int pt = p0 + tid;
            float r0 = 0.f, r1 = 0.f, r2 = 0.f, dd = 0.f;
            const ushort16* hx = &sX[tid * FSTRX];
            const ushort16* hb = &sY[tid * STRY];
#pragma unroll
            for (int k = 0; k < 32; ++k) {
                float hv = bf2f(hx[k]);
                r0 += hv * sWCf[k * 3 + 0];
                r1 += hv * sWCf[k * 3 + 1];
                r2 += hv * sWCf[k * 3 + 2];
            }
#pragma unroll
            for (int k = 0; k < 64; ++k) dd += bf2f(hb[k]) * sWDf[k];
            r0 += sWCf[96]; r1 += sWCf[97]; r2 += sWCf[98]; dd += sWCf[99];
            r0 = 1.f / (1.f + expf(-r0));
            r1 = 1.f / (1.f + expf(-r1));
            r2 = 1.f / (1.f + expf(-r2));
            float sp = (dd > 0.f) ? (dd + log1pf(expf(-dd))) : log1pf(expf(dd));
            if (f32) {
                float4 o4; o4.x = r0; o4.y = r1; o4.z = r2; o4.w = sp;
                ((float4*)out)[pt] = o4;
            } else {
                uint2 o;
                o.x = pack2(r0, r1); o.y = pack2(r2, sp);
                ((uint2*)out)[pt] = o;
            }
        }
    }
}

// ---------------------------------------------------------------------------
extern "C" void kernel_launch(void* const* d_in, const int* in_sizes, int n_in,
                              void* d_out, int out_size, void* d_ws, size_t ws_size,
                              hipStream_t stream) {
    (void)in_sizes; (void)n_in; (void)out_size;

    // SCALINGS with identical libm double math to numpy
    Scal16 sc;
    double g = exp((log(1024.0) - log(16.0)) / 15.0);
    for (int l = 0; l < 16; ++l) sc.s[l] = (float)floor(16.0 * pow(g, (double)l));

    // freqs = 2 ** float32(linspace(0,4,4))
    Freq4 fq;
    float lv[4] = {0.f, 4.f / 3.f, 8.f / 3.f, 4.f};
    for (int j = 0; j < 4; ++j) fq.f[j] = (float)pow(2.0, (double)lv[j]);

    // dense grid geometry for levels 0..5 (D = res+1, covers coord range [0,res])
    DenseP dpp;
    HashP hp;
    dpp.pfx[0] = 0;
    for (int l = 0; l < 6; ++l) {
        int D = (int)sc.s[l] + 1;
        dpp.dD[l] = D;
        dpp.pfx[l + 1] = dpp.pfx[l] + D * D * D;
    }
    for (int l = 0; l < 16; ++l) hp.s[l] = sc.s[l];
    for (int l = 0; l < 8; ++l) {
        hp.dD[l]   = (l < 6) ? dpp.dD[l] : 1;
        hp.doff[l] = (l < 6) ? dpp.pfx[l] : 0;
    }
    int ndense = dpp.pfx[6];                              // 467,959 entries

    const size_t enc_bytes   = (size_t)16 * NPTS * 4;     // 32 MiB packed-bf16 enc
    const size_t tbl2F_bytes = (size_t)10 * TSIZE * 4;    // 20 MiB packed-bf16 lvl 6..15
    const size_t dense_bytes = (size_t)ndense * 16 + 64;  // ~7.5 MB xy-patch entries
    const size_t need_new = enc_bytes + tbl2F_bytes + dense_bytes;   // ~59.1 MiB

    if (ws_size >= need_new) {
        uint32* enc   = (uint32*)d_ws;
        uint32* tbl2F = (uint32*)((char*)d_ws + enc_bytes);
        uint4*  dense4 = (uint4*)((char*)d_ws + enc_bytes + tbl2F_bytes);
        int nprep = 5120 + (ndense + 255) / 256;
        // one-time prep (cvt role is a no-op when input already bf16)
        k_prep<<<dim3(nprep), dim3(256), 0, stream>>>(d_in[0], d_in[2], (uint4*)tbl2F, dense4, dpp);
        // hashed levels 6..15 (XCD-balanced, channel floor)
        k_hashB<<<dim3(10 * NPTS / 256), dim3(256), 0, stream>>>(d_in[0], d_in[2], tbl2F, enc, hp);
        // mlp with fused dense-level gather (denseMode=1)
        k_mlp<<<dim3(512), dim3(512), 0, stream>>>(
            d_in[0], enc, d_in[1], dense4, d_in[3], d_in[4], d_in[5], d_in[6], d_in[7],
            d_in[8], d_in[9], d_in[10], d_in[11], d_in[12], d_in[13], d_in[14],
            d_out, fq, hp, 1);
    } else if (ws_size >= enc_bytes) {
        uint32* enc = (uint32*)d_ws;
        k_hash<<<dim3(2 * 8 * NPTS / 256), dim3(256), 0, stream>>>(d_in[0], d_in[2], enc, sc);
        k_mlp<<<dim3(512), dim3(512), 0, stream>>>(
            d_in[0], enc, d_in[1], (const uint4*)d_ws /*unused*/, d_in[3], d_in[4], d_in[5], d_in[6], d_in[7],
            d_in[8], d_in[9], d_in[10], d_in[11], d_in[12], d_in[13], d_in[14],
            d_out, fq, hp, 0);
    } else {
        k_fused<<<dim3(512), dim3(256), 0, stream>>>(
            d_in[0], d_in[1], d_in[2], d_in[3], d_in[4], d_in[5], d_in[6], d_in[7],
            d_in[8], d_in[9], d_in[10], d_in[11], d_in[12], d_in[13], d_in[14],
            d_out, sc, fq);
    }
}